// Round 7
// baseline (173.109 us; speedup 1.0000x reference)
//
#include <hip/hip_runtime.h>
#include <cstdint>
#include <cstddef>

typedef float v2f __attribute__((ext_vector_type(2)));

#define HID 16
#define IN  30

#define FAST_RCP(x) __builtin_amdgcn_rcpf(x)

__device__ __forceinline__ float bperm(int baddr, float v) {
    return __int_as_float(__builtin_amdgcn_ds_bpermute(baddr, __float_as_int(v)));
}
// quad_perm [1,0,3,2] (lane^1) and [2,3,0,1] (lane^2): pure-VALU quad butterfly
__device__ __forceinline__ float dq1(float v) {
    return __int_as_float(__builtin_amdgcn_mov_dpp(__float_as_int(v), 0xB1, 0xF, 0xF, true));
}
__device__ __forceinline__ float dq2(float v) {
    return __int_as_float(__builtin_amdgcn_mov_dpp(__float_as_int(v), 0x4E, 0xF, 0xF, true));
}
#define PKFMA(acc, a, b) asm("v_pk_fma_f32 %0, %1, %2, %0" : "+v"(acc) : "v"(a), "v"(b))
#define PKMUL(d, a, b)   asm("v_pk_mul_f32 %0, %1, %2"     : "=v"(d)   : "v"(a), "v"(b))

// global -> LDS direct (no VGPR round-trip); dest = wave-uniform base + lane*4
typedef __attribute__((address_space(3))) unsigned int       lds_u32_t;
typedef const __attribute__((address_space(1))) unsigned int glb_u32_t;
#define GLOAD_LDS(gp, lp) \
    __builtin_amdgcn_global_load_lds((glb_u32_t*)(gp), (lds_u32_t*)(lp), 4, 0, 0)

// ---------------- counting-sort kernels (bins by length, descending) ----------------
__global__ void k_hist(const int* __restrict__ len, int* __restrict__ hist, int B, int T) {
    int i = blockIdx.x * 256 + threadIdx.x;
    if (i < B) atomicAdd(hist + (T - len[i]), 1);
}
__global__ __launch_bounds__(512) void k_scan(const int* __restrict__ hist, int* __restrict__ off) {
    __shared__ int s[512];
    int t = threadIdx.x;
    int v = hist[t];
    s[t] = v; __syncthreads();
    int acc = v;
    for (int o = 1; o < 512; o <<= 1) {
        int add = (t >= o) ? s[t - o] : 0;
        __syncthreads();
        acc += add; s[t] = acc;
        __syncthreads();
    }
    off[t] = acc - v;   // exclusive prefix
}
__global__ void k_scatter(const int* __restrict__ len, int* __restrict__ off,
                          int* __restrict__ perm, int B, int T) {
    int i = blockIdx.x * 256 + threadIdx.x;
    if (i < B) {
        int b = T - len[i];
        int p = atomicAdd(off + b, 1);
        perm[p] = i;
    }
}

// ---------------- main GRU kernel: 4 waves/block, 1 row/wave ----------------
// lane = 4*j + q : j = hidden index (16), q = k-quarter (4)
// block-uniform lengths (sorted desc) -> blocks retire cleanly, HW refills (LPT)
__global__ __launch_bounds__(256, 4) void gru_enc_kernel(
    const float* __restrict__ x, const int* __restrict__ lengths,
    const float* __restrict__ w_ih, const float* __restrict__ w_hh,
    const float* __restrict__ b_ih, const float* __restrict__ b_hh,
    const float* __restrict__ fc1w, const float* __restrict__ fc1b,
    const float* __restrict__ fc2w, const float* __restrict__ fc2b,
    const float* __restrict__ fc3w, const float* __restrict__ fc3b,
    float* __restrict__ out, const int* __restrict__ perm,
    int B, int T)
{
    // per-wave private x staging: 4 buffers x 8 steps x 32 floats = 4 KiB/wave
    __shared__ __align__(16) float lds[4][1024];   // 16 KiB/block

    const int lane = threadIdx.x & 63;
    const int wib  = threadIdx.x >> 6;    // wave in block, 0..3
    const int q    = lane & 3;            // k-quarter (DPP quad dimension)
    const int j    = lane >> 2;           // hidden index owned

    const int pos = blockIdx.x * 4 + wib;
    if (pos >= B) return;

    const int row = perm ? perm[pos] : pos;
    const int len = lengths[row];          // wave-uniform: exactly len steps

    const float L2E = 1.4426950408889634f;
    // exp2-domain pre-scaling: r,z by -log2e; n by 2*log2e
    const float gsc[3] = { -L2E, -L2E, 2.0f * L2E };

    // ---- per-lane weights ----
    // input slice: k = q*8 .. q*8+7 (k>=30 zeroed)
    v2f wih2[3][4];
#pragma unroll
    for (int g = 0; g < 3; ++g) {
        const float* wr = w_ih + (size_t)(g * HID + j) * IN;
#pragma unroll
        for (int m = 0; m < 4; ++m) {
            int p0 = q * 8 + 2 * m;
            v2f t;
            t.x = (p0     < IN) ? wr[p0]     * gsc[g] : 0.0f;
            t.y = (p0 + 1 < IN) ? wr[p0 + 1] * gsc[g] : 0.0f;
            wih2[g][m] = t;
        }
    }
    // hidden slice: k = q*4 .. q*4+3
    v2f whh2[3][2];
#pragma unroll
    for (int g = 0; g < 3; ++g)
#pragma unroll
        for (int m = 0; m < 2; ++m) {
            const float* wr = w_hh + (size_t)(g * HID + j) * HID + q * 4 + 2 * m;
            v2f t; t.x = wr[0] * gsc[g]; t.y = wr[1] * gsc[g];
            whh2[g][m] = t;
        }

    // per-lane bias scalars, added once after the quad reduce (no acc-init movs)
    const float bR  = -L2E * (b_ih[j] + b_hh[j]);
    const float bZ  = -L2E * (b_ih[HID + j] + b_hh[HID + j]);
    const float biN = 2.0f * L2E * b_ih[2 * HID + j];
    const float bhN = 2.0f * L2E * b_hh[2 * HID + j];

    // staging source: word k = min(lane&31,29) of step (lane>>5); 64 lanes = 2 steps
    const int word  = min(lane & 31, 29);
    const int sstep = lane >> 5;
    const float* xrow = x + (size_t)row * T * IN;
    const int tcap = T - 1;

    float* ldsw = &lds[wib][0];
    const float* ldsr = ldsw + q * 8;

    // bpermute byte addresses: lane needs h_k, k = q*4+m; src lane = 4k
    int ba[4];
#pragma unroll
    for (int m = 0; m < 4; ++m) ba[m] = (16 * q + 4 * m) << 2;

    // stage chunk cc (8 steps x 32 words): 4 wide loads, 2 steps each
#define STAGE(cc) do {                                                     \
        const int t0_ = (cc) << 3;                                         \
        float* lb_ = ldsw + (((cc) & 3) << 8);                             \
        _Pragma("unroll")                                                  \
        for (int i_ = 0; i_ < 4; ++i_) {                                   \
            int ts_ = min(t0_ + (i_ << 1) + sstep, tcap);                  \
            GLOAD_LDS(xrow + (size_t)ts_ * IN + word, lb_ + (i_ << 6));    \
        }                                                                  \
    } while (0)

#define STEP(cw, s) do {                                                    \
        v2f xv0 = *(const v2f*)((cw) + ((s) << 5));                         \
        v2f xv1 = *(const v2f*)((cw) + ((s) << 5) + 2);                     \
        v2f xv2 = *(const v2f*)((cw) + ((s) << 5) + 4);                     \
        v2f xv3 = *(const v2f*)((cw) + ((s) << 5) + 6);                     \
        v2f ar, az, an, hn;                                                 \
        PKMUL(ar, wih2[0][0], xv0);                                         \
        PKMUL(az, wih2[1][0], xv0);                                         \
        PKMUL(an, wih2[2][0], xv0);                                         \
        PKFMA(ar, wih2[0][1], xv1); PKFMA(az, wih2[1][1], xv1);             \
        PKFMA(an, wih2[2][1], xv1);                                         \
        PKFMA(ar, wih2[0][2], xv2); PKFMA(az, wih2[1][2], xv2);             \
        PKFMA(an, wih2[2][2], xv2);                                         \
        PKFMA(ar, wih2[0][3], xv3); PKFMA(az, wih2[1][3], xv3);             \
        PKFMA(an, wih2[2][3], xv3);                                         \
        PKMUL(hn, whh2[2][0], hb2[0]); PKFMA(hn, whh2[2][1], hb2[1]);       \
        PKFMA(ar, whh2[0][0], hb2[0]); PKFMA(ar, whh2[0][1], hb2[1]);       \
        PKFMA(az, whh2[1][0], hb2[0]); PKFMA(az, whh2[1][1], hb2[1]);       \
        float pr  = ar.x + ar.y;  pr  += dq1(pr);  pr  += dq2(pr);          \
        float pz  = az.x + az.y;  pz  += dq1(pz);  pz  += dq2(pz);          \
        float pxn = an.x + an.y;  pxn += dq1(pxn); pxn += dq2(pxn);         \
        float phn = hn.x + hn.y;  phn += dq1(phn); phn += dq2(phn);         \
        float rg = FAST_RCP(1.0f + __builtin_exp2f(pr + bR));               \
        float zg = FAST_RCP(1.0f + __builtin_exp2f(pz + bZ));               \
        float yy = fmaf(rg, phn + bhN, pxn + biN);                          \
        float ng = fmaf(-2.0f, FAST_RCP(1.0f + __builtin_exp2f(yy)), 1.0f); \
        h_own = fmaf(zg, h_own - ng, ng);                                   \
        hb2[0].x = bperm(ba[0], h_own); hb2[0].y = bperm(ba[1], h_own);     \
        hb2[1].x = bperm(ba[2], h_own); hb2[1].y = bperm(ba[3], h_own);     \
    } while (0)

    v2f hb2[2];
    hb2[0].x = 0.0f; hb2[0].y = 0.0f; hb2[1].x = 0.0f; hb2[1].y = 0.0f;
    float h_own = 0.0f;

    const int nfull = len >> 3;
    const int rem   = len & 7;

    // prologue: 3 chunks (24 steps) in flight
    STAGE(0); STAGE(1); STAGE(2);

    int c = 0;
    for (; c < nfull; ++c) {
        // chunk c complete when <=8 staging loads outstanding (chunks c+1, c+2)
        asm volatile("s_waitcnt vmcnt(8)" ::: "memory");
        STAGE(c + 3);
        const float* cw = ldsr + ((c & 3) << 8);
        STEP(cw, 0); STEP(cw, 1); STEP(cw, 2); STEP(cw, 3);
        STEP(cw, 4); STEP(cw, 5); STEP(cw, 6); STEP(cw, 7);
    }
    if (rem) {
        asm volatile("s_waitcnt vmcnt(8)" ::: "memory");
        const float* cw = ldsr + ((c & 3) << 8);
#pragma unroll
        for (int s = 0; s < 8; ++s) {
            if (s >= rem) break;
            STEP(cw, s);
        }
    }
    // final h of this row is h_own (replicated across the quad)

    // ---- FC head (redundant across lanes; once per row) ----
    float hv[16];
#pragma unroll
    for (int k = 0; k < 16; ++k) hv[k] = __shfl(h_own, 4 * k, 64);

    float e1 = fc1b[j];
#pragma unroll
    for (int k = 0; k < 16; ++k) e1 = fmaf(fc1w[j * HID + k], hv[k], e1);

    float v1[16];
#pragma unroll
    for (int k = 0; k < 16; ++k) v1[k] = fmaxf(__shfl(e1, 4 * k, 64), 0.0f);

    float e2 = fc2b[j];
#pragma unroll
    for (int k = 0; k < 16; ++k) e2 = fmaf(fc2w[j * HID + k], v1[k], e2);

    float v2a[16];
#pragma unroll
    for (int k = 0; k < 16; ++k) v2a[k] = fmaxf(__shfl(e2, 4 * k, 64), 0.0f);

    float e3 = fc3b[j];
#pragma unroll
    for (int k = 0; k < 16; ++k) e3 = fmaf(fc3w[j * HID + k], v2a[k], e3);

    if (q == 0) out[(size_t)row * HID + j] = e3;
}

extern "C" void kernel_launch(void* const* d_in, const int* in_sizes, int n_in,
                              void* d_out, int out_size, void* d_ws, size_t ws_size,
                              hipStream_t stream) {
    const float* x    = (const float*)d_in[0];
    const int*   lens = (const int*)d_in[1];
    const float* w_ih = (const float*)d_in[2];
    const float* w_hh = (const float*)d_in[3];
    const float* b_ih = (const float*)d_in[4];
    const float* b_hh = (const float*)d_in[5];
    const float* fc1w = (const float*)d_in[6];
    const float* fc1b = (const float*)d_in[7];
    const float* fc2w = (const float*)d_in[8];
    const float* fc2b = (const float*)d_in[9];
    const float* fc3w = (const float*)d_in[10];
    const float* fc3b = (const float*)d_in[11];
    float* out = (float*)d_out;

    const int B = in_sizes[1];
    const int T = (int)(in_sizes[0] / ((size_t)B * IN));

    // ws layout (ints): perm[B] | hist[512] | off[512]
    int* wsI = (int*)d_ws;
    const size_t need = ((size_t)B + 1024) * sizeof(int);
    const bool dosort = (ws_size >= need) && (T <= 512) && (T >= 8);
    int* perm = dosort ? wsI : nullptr;
    int* hist = wsI + B;
    int* off  = wsI + B + 512;

    if (dosort) {
        hipMemsetAsync(hist, 0, 512 * sizeof(int), stream);
        k_hist<<<(B + 255) / 256, 256, 0, stream>>>(lens, hist, B, T);
        k_scan<<<1, 512, 0, stream>>>(hist, off);
        k_scatter<<<(B + 255) / 256, 256, 0, stream>>>(lens, off, perm, B, T);
    }

    const int nblk = (B + 3) / 4;   // 4 rows (waves) per 256-thread block
    gru_enc_kernel<<<nblk, 256, 0, stream>>>(x, lens, w_ih, w_hh, b_ih, b_hh,
                                             fc1w, fc1b, fc2w, fc2b, fc3w, fc3b,
                                             out, perm, B, T);
}